// Round 6
// baseline (498.294 us; speedup 1.0000x reference)
//
#include <hip/hip_runtime.h>

// HiddenMarkovGFormulaV2: N independent sequential filters over T=64 steps.
// Memory-bound streaming problem (~518 MB ideal traffic -> ~82 us floor).
//
// v7 = v6 theory, geometry fixed to fit the 64 KB per-workgroup LDS limit
// (v6's [64][129] x2 = 66,048 B failed to compile).
//
// Theory recap: five prior structures all pinned at 2.4-2.8 TB/s. The one
// dimension never varied: per-wave-INSTRUCTION spatial density (copy
// ubench: 1024 B contiguous per instruction -> 6.3 TB/s; v1-v4: 64 B
// pieces @ 256 B stride -> 2.4-2.8; v5: 16 B pieces -> 2.5, confounded by
// scratch spills). v7 makes EVERY global load/store instruction 1024 B
// dense AND consumes each row's full T in one pass (no temporal comb).
//
// Geometry:
//  * NB=64 rows per block, block = 64 threads = 1 wave. Per-array panel
//    (64 rows x 64 t) is one contiguous 16 KB span; cooperative float4
//    indexing q = tid + i*64 walks it linearly -> every load/store
//    instruction is 64 lanes x 16 B = 1024 B contiguous.
//  * LDS [64][64] per array, NO padding; element (t,r) at column
//    r ^ (t&31). Compute read col = tid ^ (t&31) is a lane permutation
//    (conflict-free); stage/readback are exactly 2-way (free).
//    2 arrays x 16 KB = 32,768 B -> 5 blocks/CU (5 x 32 KB = 160 KiB).
//  * 1-wave blocks: __syncthreads is wave-local; 5 independent blocks/CU
//    phase-stagger load/compute/store. Compute ~7 us/CU vs ~79 us/CU
//    memory -> memory is the only candidate limit.
//  * Outputs staged in-place in the same LDS slots -> ~130 VGPR, no
//    spills (v5's confound).
//  * ll: per-wave partial -> d_ws -> tiny reduce kernel (no atomics).
//  * Step math identical to v3-v5 (passed, absmax 0.0078): one v_exp
//    sigmoid, one v_log2 ll term, v_rcp for both divides, Y sign-packed.

#define TT 64          // timesteps (fixed by reference)
#define KK 3           // covariates (fixed by reference)
#define NB 64          // rows per block == threads per block (1 wave)

__global__ __launch_bounds__(256) void ll_reduce_kernel(
    const float* __restrict__ part, float* __restrict__ ll_out, int nw)
{
    float s = 0.0f;
    for (int i = threadIdx.x; i < nw; i += 256) s += part[i];
    #pragma unroll
    for (int off = 32; off > 0; off >>= 1) s += __shfl_down(s, off, 64);
    __shared__ float ws[4];
    const int wid = threadIdx.x >> 6, lane = threadIdx.x & 63;
    if (lane == 0) ws[wid] = s;
    __syncthreads();
    if (threadIdx.x == 0) *ll_out = ws[0] + ws[1] + ws[2] + ws[3];
}

// pack Y into sign bit of C (exact: Y in {0,1}, C >= 0):
// bits(1.0f)<<8 == 0x80000000, bits(0.0f) == 0.
__device__ __forceinline__ float packCY(float c, float y) {
    return __uint_as_float(__float_as_uint(c) | (__float_as_uint(y) << 8));
}

__global__ __launch_bounds__(NB) void hmm_filter_kernel(
    const float* __restrict__ G,   // (N,1)
    const float* __restrict__ S,   // (N,T)
    const float* __restrict__ C,   // (N,T)
    const float* __restrict__ Y,   // (N,T)
    const float* __restrict__ L,   // (N,K)
    const float* __restrict__ p_psi,
    const float* __restrict__ p_gS,
    const float* __restrict__ p_gC,
    const float* __restrict__ p_gG,
    const float* __restrict__ p_gGS,
    const float* __restrict__ p_gGC,
    const float* __restrict__ p_gLw,  // (1,K)
    const float* __restrict__ p_lsZ,
    const float* __restrict__ p_b0,
    const float* __restrict__ p_bZ,
    const float* __restrict__ p_bS,
    const float* __restrict__ p_bG,
    const float* __restrict__ p_bGS,
    const float* __restrict__ p_bLw,  // (1,K)
    float* __restrict__ Zf,           // (N,T)
    float* __restrict__ Zv,           // (N,T)
    float* __restrict__ ll_part,      // one partial per block (1 wave)
    int N)
{
    // [t][col], col = r ^ (t&31). No padding: 2 x 16 KB = 32 KB exactly.
    __shared__ float sS [TT][NB];     // in: S (transposed)   out: Z_filtered
    __shared__ float sCY[TT][NB];     // in: C|sign(Y)        out: Z_variance

    const int tid = threadIdx.x;      // 0..63, == lane id
    const int n0  = blockIdx.x * NB;
    const int n   = n0 + tid;
    const bool valid = (n < N);

    // --- uniform parameters (scalar-cached broadcast loads) ---
    const float psi  = p_psi[0];
    const float gS   = p_gS[0];
    const float gC   = p_gC[0];
    const float gG   = p_gG[0];
    const float gGS  = p_gGS[0];
    const float gGC  = p_gGC[0];
    const float b0   = p_b0[0];
    const float bZ   = p_bZ[0];
    const float bS   = p_bS[0];
    const float bG   = p_bG[0];
    const float bGS  = p_bGS[0];
    const float esz  = expf(p_lsZ[0]);
    const float sigma2 = esz * esz;
    const float psi2 = psi * psi;
    const float bZ2  = bZ * bZ;
    const float gw0 = p_gLw[0], gw1 = p_gLw[1], gw2 = p_gLw[2];
    const float bw0 = p_bLw[0], bw1 = p_bLw[1], bw2 = p_bLw[2];

    // --- per-n constants: fold G and L into per-thread coefficients ---
    float a_s = 0.0f, a_c = 0.0f, zbase = 0.0f, b_s = 0.0f, lbase = 0.0f;
    if (valid) {
        const float Gv = G[n];
        const float l0 = L[n * KK + 0];
        const float l1 = L[n * KK + 1];
        const float l2 = L[n * KK + 2];
        const float gL = l0 * gw0 + l1 * gw1 + l2 * gw2;
        const float bL = l0 * bw0 + l1 * bw1 + l2 * bw2;
        a_s   = gS + gGS * Gv;           // coeff of S_t in transition
        a_c   = gC + gGC * Gv;           // coeff of C_t in transition
        zbase = gG * Gv + gL;            // constant transition term
        b_s   = bS + bGS * Gv;           // coeff of S_t in logit
        lbase = b0 + bG * Gv + bL;       // constant logit term
    } else {
        lbase = b0;                      // keep math finite for dead lanes
    }

    const float4* S4 = (const float4*)S;
    const float4* C4 = (const float4*)C;
    const float4* Y4 = (const float4*)Y;
    float4* Zf4 = (float4*)Zf;
    float4* Zv4 = (float4*)Zv;

    // ---- dense cooperative load + swizzled LDS transpose ----
    // Panel per array = rows n0..n0+63, all t: contiguous 16 KB = 1024
    // float4s. q = tid + i*64 -> row r = q>>4, float4-in-row x = q&15.
    // Each wave instruction covers 64 consecutive float4s = 1024 B.
    #pragma unroll
    for (int i = 0; i < 16; ++i) {
        const int q  = tid + i * NB;
        const int r  = q >> 4;           // 0..63
        const int x  = q & 15;           // float4 within the row
        const int nn = n0 + r;
        float4 vs, vc, vy;
        if (nn < N) {
            const int g = nn * (TT / 4) + x;
            vs = S4[g]; vc = C4[g]; vy = Y4[g];
        } else {
            vs = make_float4(0, 0, 0, 0);
            vc = vs; vy = vs;
        }
        const int t0 = x * 4;
        // col = r ^ (t&31); writes are 2-way bank aliased (free)
        sS[t0 + 0][r ^ ((t0 + 0) & 31)] = vs.x;
        sS[t0 + 1][r ^ ((t0 + 1) & 31)] = vs.y;
        sS[t0 + 2][r ^ ((t0 + 2) & 31)] = vs.z;
        sS[t0 + 3][r ^ ((t0 + 3) & 31)] = vs.w;
        sCY[t0 + 0][r ^ ((t0 + 0) & 31)] = packCY(vc.x, vy.x);
        sCY[t0 + 1][r ^ ((t0 + 1) & 31)] = packCY(vc.y, vy.y);
        sCY[t0 + 2][r ^ ((t0 + 2) & 31)] = packCY(vc.z, vy.z);
        sCY[t0 + 3][r ^ ((t0 + 3) & 31)] = packCY(vc.w, vy.w);
    }
    __syncthreads();   // 1-wave block: compiles to a waitcnt, no real barrier

    // ---- sequential filter: thread tid owns row tid ----
    // Slot (t, tid^(t&31)) is read then overwritten only by this thread.
    float zm  = 0.0f;   // Z_mean
    float zv  = 1.0f;   // Z_var
    float ll2 = 0.0f;   // log-likelihood accumulated in log2 domain

    #pragma unroll
    for (int t = 0; t < TT; ++t) {
        const int col      = tid ^ (t & 31);   // lane permutation: no conflict
        const float s      = sS[t][col];
        const unsigned cyb = __float_as_uint(sCY[t][col]);
        const float c      = __uint_as_float(cyb & 0x7fffffffu);
        const bool  yb     = (cyb >> 31) != 0u;

        const float zpred = fmaf(psi, zm, fmaf(a_s, s, fmaf(a_c, c, zbase)));
        const float zpvar = fmaf(psi2, zv, sigma2);

        float logit = fmaf(bZ, zpred, fmaf(b_s, s, lbase));
        logit = fminf(fmaxf(logit, -20.0f), 20.0f);
        // sigmoid: one v_exp_f32 + one v_rcp_f32
        const float p   = __builtin_amdgcn_rcpf(1.0f + __expf(-logit));
        const float omp = 1.0f - p;

        const float ymp = yb ? omp : -p;     // (y - p), y in {0,1}
        const float sel = yb ? p : omp;      // prob of observed outcome

        const float hess = fmaf(bZ2 * p, omp, 1e-6f);
        // 1/(1/zpvar + hess) == zpvar/(1 + zpvar*hess): one v_rcp_f32
        const float zpostvar  = zpvar * __builtin_amdgcn_rcpf(fmaf(zpvar, hess, 1.0f));
        const float zpostmean = fmaf(zpostvar * bZ, ymp, zpred);

        // y*log(p+e) + (1-y)*log(1-p+e) == log(sel+e) for binary y;
        // accumulate log2, scale by ln2 once after the loop.
        ll2 += __log2f(sel + 1e-10f);

        zm = zpostmean;
        zv = zpostvar;
        sS [t][col] = zpostmean;   // stage Z_filtered
        sCY[t][col] = zpostvar;    // stage Z_variance
    }
    __syncthreads();

    // ---- dense cooperative stores (1024 B per wave instruction) ----
    #pragma unroll
    for (int i = 0; i < 16; ++i) {
        const int q  = tid + i * NB;
        const int r  = q >> 4;
        const int x  = q & 15;
        const int nn = n0 + r;
        if (nn < N) {
            const int t0 = x * 4;
            float4 vf, vv;
            vf.x = sS[t0 + 0][r ^ ((t0 + 0) & 31)];
            vf.y = sS[t0 + 1][r ^ ((t0 + 1) & 31)];
            vf.z = sS[t0 + 2][r ^ ((t0 + 2) & 31)];
            vf.w = sS[t0 + 3][r ^ ((t0 + 3) & 31)];
            vv.x = sCY[t0 + 0][r ^ ((t0 + 0) & 31)];
            vv.y = sCY[t0 + 1][r ^ ((t0 + 1) & 31)];
            vv.z = sCY[t0 + 2][r ^ ((t0 + 2) & 31)];
            vv.w = sCY[t0 + 3][r ^ ((t0 + 3) & 31)];
            const int g = nn * (TT / 4) + x;
            Zf4[g] = vf;
            Zv4[g] = vv;
        }
    }

    // ---- ll reduction: wave shuffle -> one partial per block ----
    float ll = valid ? ll2 * 0.69314718055994531f : 0.0f;
    #pragma unroll
    for (int off = 32; off > 0; off >>= 1) {
        ll += __shfl_down(ll, off, 64);
    }
    if (tid == 0) ll_part[blockIdx.x] = ll;
}

extern "C" void kernel_launch(void* const* d_in, const int* in_sizes, int n_in,
                              void* d_out, int out_size, void* d_ws, size_t ws_size,
                              hipStream_t stream) {
    const int N = in_sizes[0];  // G is (N,1)

    const float* G   = (const float*)d_in[0];
    const float* S   = (const float*)d_in[1];
    const float* C   = (const float*)d_in[2];
    const float* Y   = (const float*)d_in[3];
    const float* L   = (const float*)d_in[4];
    const float* psi = (const float*)d_in[5];
    const float* gS  = (const float*)d_in[6];
    const float* gC  = (const float*)d_in[7];
    const float* gG  = (const float*)d_in[8];
    const float* gGS = (const float*)d_in[9];
    const float* gGC = (const float*)d_in[10];
    const float* gLw = (const float*)d_in[11];
    const float* lsZ = (const float*)d_in[12];
    const float* b0  = (const float*)d_in[13];
    const float* bZ  = (const float*)d_in[14];
    const float* bS  = (const float*)d_in[15];
    const float* bG  = (const float*)d_in[16];
    const float* bGS = (const float*)d_in[17];
    const float* bLw = (const float*)d_in[18];

    float* out = (float*)d_out;
    float* Zf = out;
    float* Zv = out + (size_t)N * TT;
    float* ll = out + (size_t)2 * N * TT;

    float* ll_part = (float*)d_ws;   // one float per block of workspace

    const int blocks = (N + NB - 1) / NB;
    hmm_filter_kernel<<<blocks, NB, 0, stream>>>(
        G, S, C, Y, L, psi, gS, gC, gG, gGS, gGC, gLw, lsZ,
        b0, bZ, bS, bG, bGS, bLw, Zf, Zv, ll_part, N);
    ll_reduce_kernel<<<1, 256, 0, stream>>>(ll_part, ll, blocks);
}

// Round 7
// 488.628 us; speedup vs baseline: 1.0198x; 1.0198x over previous
//
#include <hip/hip_runtime.h>

// HiddenMarkovGFormulaV2: N independent sequential filters over T=64 steps.
// Memory-bound streaming problem (~518 MB ideal traffic -> ~82 us floor).
//
// v8 = v7 + NONTEMPORAL OUTPUT STORES. Diagnosis across v3/v4/v5/v7: with
// read traffic varying 153-300 MB and four different access structures,
// wall time tracks WRITE_SIZE/1.1 TB/s (1.09/1.14/1.12/1.09) -> the kernel
// is WRITE-bound on a ~1.1 TB/s effective write path, not read-bound.
// Candidate mechanism: write-allocate/RFO + dirty-eviction in L2/L3 halves
// effective DRAM write rate. Fix under test: nt (nontemporal) stores ->
// no-allocate, full-line streaming writes.
//
// Carried from v7 (184 us, clean counters):
//  * NB=64 rows/block, 1 wave/block; full T=64 per pass (no temporal comb).
//  * Every global load/store instruction: 64 lanes x 16 B = 1024 B dense.
//  * LDS [64][64] x2, no pad, XOR swizzle col = r^(t&31): 32,768 B exactly
//    -> 5 blocks/CU; compute phase is a lane permutation (conflict-free),
//    stage/readback 2-way (free).
//  * Loads stay CACHED (L3 retains ~half the inputs across iterations:
//    FETCH 153 MB < 313 MB ideal).
//  * ll: per-wave partial -> d_ws -> tiny reduce kernel (no atomics).
//  * Step math identical to v3-v7 (passed, absmax 0.0078): one v_exp
//    sigmoid, one v_log2 ll term, v_rcp for both divides, Y sign-packed.

#define TT 64          // timesteps (fixed by reference)
#define KK 3           // covariates (fixed by reference)
#define NB 64          // rows per block == threads per block (1 wave)

typedef float f4_t __attribute__((ext_vector_type(4)));

// nontemporal 16 B store: full-line streaming write, no cache allocate
__device__ __forceinline__ void nt_store4(float4* p, float x, float y,
                                          float z, float w) {
    f4_t v = {x, y, z, w};
    __builtin_nontemporal_store(v, (f4_t*)p);
}

__global__ __launch_bounds__(256) void ll_reduce_kernel(
    const float* __restrict__ part, float* __restrict__ ll_out, int nw)
{
    float s = 0.0f;
    for (int i = threadIdx.x; i < nw; i += 256) s += part[i];
    #pragma unroll
    for (int off = 32; off > 0; off >>= 1) s += __shfl_down(s, off, 64);
    __shared__ float ws[4];
    const int wid = threadIdx.x >> 6, lane = threadIdx.x & 63;
    if (lane == 0) ws[wid] = s;
    __syncthreads();
    if (threadIdx.x == 0) *ll_out = ws[0] + ws[1] + ws[2] + ws[3];
}

// pack Y into sign bit of C (exact: Y in {0,1}, C >= 0):
// bits(1.0f)<<8 == 0x80000000, bits(0.0f) == 0.
__device__ __forceinline__ float packCY(float c, float y) {
    return __uint_as_float(__float_as_uint(c) | (__float_as_uint(y) << 8));
}

__global__ __launch_bounds__(NB) void hmm_filter_kernel(
    const float* __restrict__ G,   // (N,1)
    const float* __restrict__ S,   // (N,T)
    const float* __restrict__ C,   // (N,T)
    const float* __restrict__ Y,   // (N,T)
    const float* __restrict__ L,   // (N,K)
    const float* __restrict__ p_psi,
    const float* __restrict__ p_gS,
    const float* __restrict__ p_gC,
    const float* __restrict__ p_gG,
    const float* __restrict__ p_gGS,
    const float* __restrict__ p_gGC,
    const float* __restrict__ p_gLw,  // (1,K)
    const float* __restrict__ p_lsZ,
    const float* __restrict__ p_b0,
    const float* __restrict__ p_bZ,
    const float* __restrict__ p_bS,
    const float* __restrict__ p_bG,
    const float* __restrict__ p_bGS,
    const float* __restrict__ p_bLw,  // (1,K)
    float* __restrict__ Zf,           // (N,T)
    float* __restrict__ Zv,           // (N,T)
    float* __restrict__ ll_part,      // one partial per block (1 wave)
    int N)
{
    // [t][col], col = r ^ (t&31). No padding: 2 x 16 KB = 32 KB exactly.
    __shared__ float sS [TT][NB];     // in: S (transposed)   out: Z_filtered
    __shared__ float sCY[TT][NB];     // in: C|sign(Y)        out: Z_variance

    const int tid = threadIdx.x;      // 0..63, == lane id
    const int n0  = blockIdx.x * NB;
    const int n   = n0 + tid;
    const bool valid = (n < N);

    // --- uniform parameters (scalar-cached broadcast loads) ---
    const float psi  = p_psi[0];
    const float gS   = p_gS[0];
    const float gC   = p_gC[0];
    const float gG   = p_gG[0];
    const float gGS  = p_gGS[0];
    const float gGC  = p_gGC[0];
    const float b0   = p_b0[0];
    const float bZ   = p_bZ[0];
    const float bS   = p_bS[0];
    const float bG   = p_bG[0];
    const float bGS  = p_bGS[0];
    const float esz  = expf(p_lsZ[0]);
    const float sigma2 = esz * esz;
    const float psi2 = psi * psi;
    const float bZ2  = bZ * bZ;
    const float gw0 = p_gLw[0], gw1 = p_gLw[1], gw2 = p_gLw[2];
    const float bw0 = p_bLw[0], bw1 = p_bLw[1], bw2 = p_bLw[2];

    // --- per-n constants: fold G and L into per-thread coefficients ---
    float a_s = 0.0f, a_c = 0.0f, zbase = 0.0f, b_s = 0.0f, lbase = 0.0f;
    if (valid) {
        const float Gv = G[n];
        const float l0 = L[n * KK + 0];
        const float l1 = L[n * KK + 1];
        const float l2 = L[n * KK + 2];
        const float gL = l0 * gw0 + l1 * gw1 + l2 * gw2;
        const float bL = l0 * bw0 + l1 * bw1 + l2 * bw2;
        a_s   = gS + gGS * Gv;           // coeff of S_t in transition
        a_c   = gC + gGC * Gv;           // coeff of C_t in transition
        zbase = gG * Gv + gL;            // constant transition term
        b_s   = bS + bGS * Gv;           // coeff of S_t in logit
        lbase = b0 + bG * Gv + bL;       // constant logit term
    } else {
        lbase = b0;                      // keep math finite for dead lanes
    }

    const float4* S4 = (const float4*)S;
    const float4* C4 = (const float4*)C;
    const float4* Y4 = (const float4*)Y;
    float4* Zf4 = (float4*)Zf;
    float4* Zv4 = (float4*)Zv;

    // ---- dense cooperative load + swizzled LDS transpose ----
    // Panel per array = rows n0..n0+63, all t: contiguous 16 KB = 1024
    // float4s. q = tid + i*64 -> row r = q>>4, float4-in-row x = q&15.
    // Each wave instruction covers 64 consecutive float4s = 1024 B.
    #pragma unroll
    for (int i = 0; i < 16; ++i) {
        const int q  = tid + i * NB;
        const int r  = q >> 4;           // 0..63
        const int x  = q & 15;           // float4 within the row
        const int nn = n0 + r;
        float4 vs, vc, vy;
        if (nn < N) {
            const int g = nn * (TT / 4) + x;
            vs = S4[g]; vc = C4[g]; vy = Y4[g];
        } else {
            vs = make_float4(0, 0, 0, 0);
            vc = vs; vy = vs;
        }
        const int t0 = x * 4;
        // col = r ^ (t&31); writes are <=2-way bank aliased (free)
        sS[t0 + 0][r ^ ((t0 + 0) & 31)] = vs.x;
        sS[t0 + 1][r ^ ((t0 + 1) & 31)] = vs.y;
        sS[t0 + 2][r ^ ((t0 + 2) & 31)] = vs.z;
        sS[t0 + 3][r ^ ((t0 + 3) & 31)] = vs.w;
        sCY[t0 + 0][r ^ ((t0 + 0) & 31)] = packCY(vc.x, vy.x);
        sCY[t0 + 1][r ^ ((t0 + 1) & 31)] = packCY(vc.y, vy.y);
        sCY[t0 + 2][r ^ ((t0 + 2) & 31)] = packCY(vc.z, vy.z);
        sCY[t0 + 3][r ^ ((t0 + 3) & 31)] = packCY(vc.w, vy.w);
    }
    __syncthreads();   // 1-wave block: compiles to a waitcnt, no real barrier

    // ---- sequential filter: thread tid owns row tid ----
    // Slot (t, tid^(t&31)) is read then overwritten only by this thread.
    float zm  = 0.0f;   // Z_mean
    float zv  = 1.0f;   // Z_var
    float ll2 = 0.0f;   // log-likelihood accumulated in log2 domain

    #pragma unroll
    for (int t = 0; t < TT; ++t) {
        const int col      = tid ^ (t & 31);   // lane permutation: no conflict
        const float s      = sS[t][col];
        const unsigned cyb = __float_as_uint(sCY[t][col]);
        const float c      = __uint_as_float(cyb & 0x7fffffffu);
        const bool  yb     = (cyb >> 31) != 0u;

        const float zpred = fmaf(psi, zm, fmaf(a_s, s, fmaf(a_c, c, zbase)));
        const float zpvar = fmaf(psi2, zv, sigma2);

        float logit = fmaf(bZ, zpred, fmaf(b_s, s, lbase));
        logit = fminf(fmaxf(logit, -20.0f), 20.0f);
        // sigmoid: one v_exp_f32 + one v_rcp_f32
        const float p   = __builtin_amdgcn_rcpf(1.0f + __expf(-logit));
        const float omp = 1.0f - p;

        const float ymp = yb ? omp : -p;     // (y - p), y in {0,1}
        const float sel = yb ? p : omp;      // prob of observed outcome

        const float hess = fmaf(bZ2 * p, omp, 1e-6f);
        // 1/(1/zpvar + hess) == zpvar/(1 + zpvar*hess): one v_rcp_f32
        const float zpostvar  = zpvar * __builtin_amdgcn_rcpf(fmaf(zpvar, hess, 1.0f));
        const float zpostmean = fmaf(zpostvar * bZ, ymp, zpred);

        // y*log(p+e) + (1-y)*log(1-p+e) == log(sel+e) for binary y;
        // accumulate log2, scale by ln2 once after the loop.
        ll2 += __log2f(sel + 1e-10f);

        zm = zpostmean;
        zv = zpostvar;
        sS [t][col] = zpostmean;   // stage Z_filtered
        sCY[t][col] = zpostvar;    // stage Z_variance
    }
    __syncthreads();

    // ---- dense cooperative NONTEMPORAL stores (1024 B per instruction,
    //      Zf/Zv interleaved to keep both DRAM streams fed) ----
    #pragma unroll
    for (int i = 0; i < 16; ++i) {
        const int q  = tid + i * NB;
        const int r  = q >> 4;
        const int x  = q & 15;
        const int nn = n0 + r;
        if (nn < N) {
            const int t0 = x * 4;
            const int g  = nn * (TT / 4) + x;
            nt_store4(&Zf4[g],
                      sS[t0 + 0][r ^ ((t0 + 0) & 31)],
                      sS[t0 + 1][r ^ ((t0 + 1) & 31)],
                      sS[t0 + 2][r ^ ((t0 + 2) & 31)],
                      sS[t0 + 3][r ^ ((t0 + 3) & 31)]);
            nt_store4(&Zv4[g],
                      sCY[t0 + 0][r ^ ((t0 + 0) & 31)],
                      sCY[t0 + 1][r ^ ((t0 + 1) & 31)],
                      sCY[t0 + 2][r ^ ((t0 + 2) & 31)],
                      sCY[t0 + 3][r ^ ((t0 + 3) & 31)]);
        }
    }

    // ---- ll reduction: wave shuffle -> one partial per block ----
    float ll = valid ? ll2 * 0.69314718055994531f : 0.0f;
    #pragma unroll
    for (int off = 32; off > 0; off >>= 1) {
        ll += __shfl_down(ll, off, 64);
    }
    if (tid == 0) ll_part[blockIdx.x] = ll;
}

extern "C" void kernel_launch(void* const* d_in, const int* in_sizes, int n_in,
                              void* d_out, int out_size, void* d_ws, size_t ws_size,
                              hipStream_t stream) {
    const int N = in_sizes[0];  // G is (N,1)

    const float* G   = (const float*)d_in[0];
    const float* S   = (const float*)d_in[1];
    const float* C   = (const float*)d_in[2];
    const float* Y   = (const float*)d_in[3];
    const float* L   = (const float*)d_in[4];
    const float* psi = (const float*)d_in[5];
    const float* gS  = (const float*)d_in[6];
    const float* gC  = (const float*)d_in[7];
    const float* gG  = (const float*)d_in[8];
    const float* gGS = (const float*)d_in[9];
    const float* gGC = (const float*)d_in[10];
    const float* gLw = (const float*)d_in[11];
    const float* lsZ = (const float*)d_in[12];
    const float* b0  = (const float*)d_in[13];
    const float* bZ  = (const float*)d_in[14];
    const float* bS  = (const float*)d_in[15];
    const float* bG  = (const float*)d_in[16];
    const float* bGS = (const float*)d_in[17];
    const float* bLw = (const float*)d_in[18];

    float* out = (float*)d_out;
    float* Zf = out;
    float* Zv = out + (size_t)N * TT;
    float* ll = out + (size_t)2 * N * TT;

    float* ll_part = (float*)d_ws;   // one float per block of workspace

    const int blocks = (N + NB - 1) / NB;
    hmm_filter_kernel<<<blocks, NB, 0, stream>>>(
        G, S, C, Y, L, psi, gS, gC, gG, gGS, gGC, gLw, lsZ,
        b0, bZ, bS, bG, bGS, bLw, Zf, Zv, ll_part, N);
    ll_reduce_kernel<<<1, 256, 0, stream>>>(ll_part, ll, blocks);
}

// Round 8
// 481.407 us; speedup vs baseline: 1.0351x; 1.0150x over previous
//
#include <hip/hip_runtime.h>

// HiddenMarkovGFormulaV2: N independent sequential filters over T=64 steps.
// Memory-bound streaming problem (~518 MB ideal traffic -> ~82 us floor).
//
// v9: discriminating experiment between the two surviving models:
//  (A) write path drains at ~1.1 TB/s regardless of kernel (fits
//      dur = WRITE/1.1 within 4% for v3..v8)  -> v9 changes nothing.
//  (B) per-CU memory concurrency: achieved BW tracks resident waves x
//      flow continuity (v7: 3.3 waves -> 7.5 GB/s/CU; v4: 12 -> 10.6;
//      copy ubench: 8 continuous -> 24.6)      -> v9 roughly doubles BW.
// v9 = v7 structure with HALF panels: 32 rows/block -> LDS 16 KB ->
// 10 blocks/CU (2x v7 residency), 12500 1-wave blocks (4.9 generations
// per CU -> launch staggering smooths the burst-drain-idle flow).
//
// Carried from v7 (184 us, clean):
//  * Full T=64 per row in one pass (no temporal comb).
//  * Every global load/store instruction: 64 lanes x 16 B = 1024 B
//    contiguous (4 full rows per instruction).
//  * XOR swizzle col = r ^ (t&31), r in 0..31: compute phase is a lane
//    permutation (broadcast for the idle half-wave), stage/readback
//    <=2-way (free). LDS 2 x [64][32] x 4 B = 16,384 B exactly.
//  * Lanes 32-63 idle during the scan (VALU 16%->~32%, harmless) but
//    participate in all dense cooperative load/store phases.
//  * ll: per-block partial -> d_ws -> tiny reduce kernel (no atomics).
//  * Step math identical to v3-v8 (passed, absmax 0.0078).

#define TT 64          // timesteps (fixed by reference)
#define KK 3           // covariates (fixed by reference)
#define NR 32          // rows per block
#define BT 64          // threads per block (1 wave)

__global__ __launch_bounds__(256) void ll_reduce_kernel(
    const float* __restrict__ part, float* __restrict__ ll_out, int nw)
{
    float s = 0.0f;
    for (int i = threadIdx.x; i < nw; i += 256) s += part[i];
    #pragma unroll
    for (int off = 32; off > 0; off >>= 1) s += __shfl_down(s, off, 64);
    __shared__ float ws[4];
    const int wid = threadIdx.x >> 6, lane = threadIdx.x & 63;
    if (lane == 0) ws[wid] = s;
    __syncthreads();
    if (threadIdx.x == 0) *ll_out = ws[0] + ws[1] + ws[2] + ws[3];
}

// pack Y into sign bit of C (exact: Y in {0,1}, C >= 0):
// bits(1.0f)<<8 == 0x80000000, bits(0.0f) == 0.
__device__ __forceinline__ float packCY(float c, float y) {
    return __uint_as_float(__float_as_uint(c) | (__float_as_uint(y) << 8));
}

__global__ __launch_bounds__(BT) void hmm_filter_kernel(
    const float* __restrict__ G,   // (N,1)
    const float* __restrict__ S,   // (N,T)
    const float* __restrict__ C,   // (N,T)
    const float* __restrict__ Y,   // (N,T)
    const float* __restrict__ L,   // (N,K)
    const float* __restrict__ p_psi,
    const float* __restrict__ p_gS,
    const float* __restrict__ p_gC,
    const float* __restrict__ p_gG,
    const float* __restrict__ p_gGS,
    const float* __restrict__ p_gGC,
    const float* __restrict__ p_gLw,  // (1,K)
    const float* __restrict__ p_lsZ,
    const float* __restrict__ p_b0,
    const float* __restrict__ p_bZ,
    const float* __restrict__ p_bS,
    const float* __restrict__ p_bG,
    const float* __restrict__ p_bGS,
    const float* __restrict__ p_bLw,  // (1,K)
    float* __restrict__ Zf,           // (N,T)
    float* __restrict__ Zv,           // (N,T)
    float* __restrict__ ll_part,      // one partial per block
    int N)
{
    // [t][col], col = r ^ (t&31), r in 0..31. 2 x 8 KB = 16,384 B exactly.
    __shared__ float sS [TT][NR];     // in: S (transposed)   out: Z_filtered
    __shared__ float sCY[TT][NR];     // in: C|sign(Y)        out: Z_variance

    const int tid = threadIdx.x;      // 0..63, == lane id
    const int n0  = blockIdx.x * NR;
    const int rl  = tid & 31;         // row owned during the scan
    const int n   = n0 + rl;
    const bool valid = (tid < 32) && (n < N);

    // --- uniform parameters (scalar-cached broadcast loads) ---
    const float psi  = p_psi[0];
    const float gS   = p_gS[0];
    const float gC   = p_gC[0];
    const float gG   = p_gG[0];
    const float gGS  = p_gGS[0];
    const float gGC  = p_gGC[0];
    const float b0   = p_b0[0];
    const float bZ   = p_bZ[0];
    const float bS   = p_bS[0];
    const float bG   = p_bG[0];
    const float bGS  = p_bGS[0];
    const float esz  = expf(p_lsZ[0]);
    const float sigma2 = esz * esz;
    const float psi2 = psi * psi;
    const float bZ2  = bZ * bZ;
    const float gw0 = p_gLw[0], gw1 = p_gLw[1], gw2 = p_gLw[2];
    const float bw0 = p_bLw[0], bw1 = p_bLw[1], bw2 = p_bLw[2];

    // --- per-n constants: fold G and L into per-thread coefficients ---
    float a_s = 0.0f, a_c = 0.0f, zbase = 0.0f, b_s = 0.0f, lbase = 0.0f;
    if (valid) {
        const float Gv = G[n];
        const float l0 = L[n * KK + 0];
        const float l1 = L[n * KK + 1];
        const float l2 = L[n * KK + 2];
        const float gL = l0 * gw0 + l1 * gw1 + l2 * gw2;
        const float bL = l0 * bw0 + l1 * bw1 + l2 * bw2;
        a_s   = gS + gGS * Gv;           // coeff of S_t in transition
        a_c   = gC + gGC * Gv;           // coeff of C_t in transition
        zbase = gG * Gv + gL;            // constant transition term
        b_s   = bS + bGS * Gv;           // coeff of S_t in logit
        lbase = b0 + bG * Gv + bL;       // constant logit term
    } else {
        lbase = b0;                      // keep math finite for idle lanes
    }

    const float4* S4 = (const float4*)S;
    const float4* C4 = (const float4*)C;
    const float4* Y4 = (const float4*)Y;
    float4* Zf4 = (float4*)Zf;
    float4* Zv4 = (float4*)Zv;

    // ---- dense cooperative load + swizzled LDS transpose ----
    // Panel per array = rows n0..n0+31, all t: contiguous 8 KB = 512
    // float4s. q = tid + i*64 -> row r = q>>4, float4-in-row x = q&15.
    // Each wave instruction covers 64 consecutive float4s = 4 full rows
    // = 1024 B contiguous.
    #pragma unroll
    for (int i = 0; i < 8; ++i) {
        const int q  = tid + i * BT;
        const int r  = q >> 4;           // 0..31
        const int x  = q & 15;           // float4 within the row
        const int nn = n0 + r;
        float4 vs, vc, vy;
        if (nn < N) {
            const int g = nn * (TT / 4) + x;
            vs = S4[g]; vc = C4[g]; vy = Y4[g];
        } else {
            vs = make_float4(0, 0, 0, 0);
            vc = vs; vy = vs;
        }
        const int t0 = x * 4;
        // col = r ^ (t&31): within an instruction the 16 lanes of a
        // 4-lane r-group span distinct t -> distinct banks; across
        // r-groups <=2-way (free).
        sS[t0 + 0][r ^ ((t0 + 0) & 31)] = vs.x;
        sS[t0 + 1][r ^ ((t0 + 1) & 31)] = vs.y;
        sS[t0 + 2][r ^ ((t0 + 2) & 31)] = vs.z;
        sS[t0 + 3][r ^ ((t0 + 3) & 31)] = vs.w;
        sCY[t0 + 0][r ^ ((t0 + 0) & 31)] = packCY(vc.x, vy.x);
        sCY[t0 + 1][r ^ ((t0 + 1) & 31)] = packCY(vc.y, vy.y);
        sCY[t0 + 2][r ^ ((t0 + 2) & 31)] = packCY(vc.z, vy.z);
        sCY[t0 + 3][r ^ ((t0 + 3) & 31)] = packCY(vc.w, vy.w);
    }
    __syncthreads();   // 1-wave block: compiles to a waitcnt, no real barrier

    // ---- sequential filter: lane rl (<32) owns row rl; lanes 32-63
    //      read broadcast duplicates and are masked off the writes ----
    float zm  = 0.0f;   // Z_mean
    float zv  = 1.0f;   // Z_var
    float ll2 = 0.0f;   // log-likelihood accumulated in log2 domain

    #pragma unroll
    for (int t = 0; t < TT; ++t) {
        const int col      = rl ^ (t & 31);    // lane permutation: no conflict
        const float s      = sS[t][col];
        const unsigned cyb = __float_as_uint(sCY[t][col]);
        const float c      = __uint_as_float(cyb & 0x7fffffffu);
        const bool  yb     = (cyb >> 31) != 0u;

        const float zpred = fmaf(psi, zm, fmaf(a_s, s, fmaf(a_c, c, zbase)));
        const float zpvar = fmaf(psi2, zv, sigma2);

        float logit = fmaf(bZ, zpred, fmaf(b_s, s, lbase));
        logit = fminf(fmaxf(logit, -20.0f), 20.0f);
        // sigmoid: one v_exp_f32 + one v_rcp_f32
        const float p   = __builtin_amdgcn_rcpf(1.0f + __expf(-logit));
        const float omp = 1.0f - p;

        const float ymp = yb ? omp : -p;     // (y - p), y in {0,1}
        const float sel = yb ? p : omp;      // prob of observed outcome

        const float hess = fmaf(bZ2 * p, omp, 1e-6f);
        // 1/(1/zpvar + hess) == zpvar/(1 + zpvar*hess): one v_rcp_f32
        const float zpostvar  = zpvar * __builtin_amdgcn_rcpf(fmaf(zpvar, hess, 1.0f));
        const float zpostmean = fmaf(zpostvar * bZ, ymp, zpred);

        // y*log(p+e) + (1-y)*log(1-p+e) == log(sel+e) for binary y;
        // accumulate log2, scale by ln2 once after the loop.
        ll2 += __log2f(sel + 1e-10f);

        zm = zpostmean;
        zv = zpostvar;
        if (tid < 32) {
            sS [t][col] = zpostmean;   // stage Z_filtered
            sCY[t][col] = zpostvar;    // stage Z_variance
        }
    }
    __syncthreads();

    // ---- dense cooperative stores (1024 B per wave instruction) ----
    #pragma unroll
    for (int i = 0; i < 8; ++i) {
        const int q  = tid + i * BT;
        const int r  = q >> 4;
        const int x  = q & 15;
        const int nn = n0 + r;
        if (nn < N) {
            const int t0 = x * 4;
            float4 vf, vv;
            vf.x = sS[t0 + 0][r ^ ((t0 + 0) & 31)];
            vf.y = sS[t0 + 1][r ^ ((t0 + 1) & 31)];
            vf.z = sS[t0 + 2][r ^ ((t0 + 2) & 31)];
            vf.w = sS[t0 + 3][r ^ ((t0 + 3) & 31)];
            vv.x = sCY[t0 + 0][r ^ ((t0 + 0) & 31)];
            vv.y = sCY[t0 + 1][r ^ ((t0 + 1) & 31)];
            vv.z = sCY[t0 + 2][r ^ ((t0 + 2) & 31)];
            vv.w = sCY[t0 + 3][r ^ ((t0 + 3) & 31)];
            const int g = nn * (TT / 4) + x;
            Zf4[g] = vf;
            Zv4[g] = vv;
        }
    }

    // ---- ll reduction: wave shuffle -> one partial per block ----
    float ll = valid ? ll2 * 0.69314718055994531f : 0.0f;
    #pragma unroll
    for (int off = 32; off > 0; off >>= 1) {
        ll += __shfl_down(ll, off, 64);
    }
    if (tid == 0) ll_part[blockIdx.x] = ll;
}

extern "C" void kernel_launch(void* const* d_in, const int* in_sizes, int n_in,
                              void* d_out, int out_size, void* d_ws, size_t ws_size,
                              hipStream_t stream) {
    const int N = in_sizes[0];  // G is (N,1)

    const float* G   = (const float*)d_in[0];
    const float* S   = (const float*)d_in[1];
    const float* C   = (const float*)d_in[2];
    const float* Y   = (const float*)d_in[3];
    const float* L   = (const float*)d_in[4];
    const float* psi = (const float*)d_in[5];
    const float* gS  = (const float*)d_in[6];
    const float* gC  = (const float*)d_in[7];
    const float* gG  = (const float*)d_in[8];
    const float* gGS = (const float*)d_in[9];
    const float* gGC = (const float*)d_in[10];
    const float* gLw = (const float*)d_in[11];
    const float* lsZ = (const float*)d_in[12];
    const float* b0  = (const float*)d_in[13];
    const float* bZ  = (const float*)d_in[14];
    const float* bS  = (const float*)d_in[15];
    const float* bG  = (const float*)d_in[16];
    const float* bGS = (const float*)d_in[17];
    const float* bLw = (const float*)d_in[18];

    float* out = (float*)d_out;
    float* Zf = out;
    float* Zv = out + (size_t)N * TT;
    float* ll = out + (size_t)2 * N * TT;

    float* ll_part = (float*)d_ws;   // one float per block of workspace

    const int blocks = (N + NR - 1) / NR;
    hmm_filter_kernel<<<blocks, BT, 0, stream>>>(
        G, S, C, Y, L, psi, gS, gC, gG, gGS, gGC, gLw, lsZ,
        b0, bZ, bS, bG, bGS, bLw, Zf, Zv, ll_part, N);
    ll_reduce_kernel<<<1, 256, 0, stream>>>(ll_part, ll, blocks);
}